// Round 2
// baseline (75443.726 us; speedup 1.0000x reference)
//
#include <hip/hip_runtime.h>
#include <math.h>

// Round 1: same structure as R0, but workspace shrunk 316MB -> 119MB.
//   - x-side gate GEMMs chunked in time (CH=50) into a rotating 13MB buffer
//   - he overlays bufB, ysp overlays the gate chunk buffer
// Theory: R0's abort was d_ws overflow (GPU memory fault).

#define T_    800
#define B_    16
#define FEAT_ 120
#define H_    512
#define H2_   1024
#define H4_   2048
#define CC_   5000
#define NL_   100
#define CH_   50

#define BM 128
#define BN 128
#define BK 8

// C[m*ldc + n] = sum_k A[m*K+k] * W[n*K+k] + bias[n]     (requires K % 8 == 0)
__global__ __launch_bounds__(256) void gemm_bt(
    const float* __restrict__ A, const float* __restrict__ W,
    const float* __restrict__ bias, float* __restrict__ C,
    int M, int N, int K, int ldc)
{
  __shared__ float As[BK][BM + 8];
  __shared__ float Ws[BK][BN + 8];
  const int tid = threadIdx.x;
  const int tx = tid & 15, ty = tid >> 4;
  const int row0 = blockIdx.y * BM, col0 = blockIdx.x * BN;
  const int lr = tid >> 1, lh = (tid & 1) * 4;
  float acc[8][8];
#pragma unroll
  for (int i = 0; i < 8; i++)
#pragma unroll
    for (int j = 0; j < 8; j++) acc[i][j] = 0.f;

  for (int kt = 0; kt < K; kt += BK) {
    float4 av = make_float4(0.f, 0.f, 0.f, 0.f);
    float4 wv = make_float4(0.f, 0.f, 0.f, 0.f);
    const int ar = row0 + lr;
    if (ar < M) av = *(const float4*)(A + (long)ar * K + kt + lh);
    const int wr = col0 + lr;
    if (wr < N) wv = *(const float4*)(W + (long)wr * K + kt + lh);
    __syncthreads();
    As[lh + 0][lr] = av.x; As[lh + 1][lr] = av.y;
    As[lh + 2][lr] = av.z; As[lh + 3][lr] = av.w;
    Ws[lh + 0][lr] = wv.x; Ws[lh + 1][lr] = wv.y;
    Ws[lh + 2][lr] = wv.z; Ws[lh + 3][lr] = wv.w;
    __syncthreads();
#pragma unroll
    for (int k = 0; k < BK; k++) {
      float4 a0 = *(const float4*)&As[k][ty * 8];
      float4 a1 = *(const float4*)&As[k][ty * 8 + 4];
      float4 w0 = *(const float4*)&Ws[k][tx * 8];
      float4 w1 = *(const float4*)&Ws[k][tx * 8 + 4];
      float a[8] = {a0.x, a0.y, a0.z, a0.w, a1.x, a1.y, a1.z, a1.w};
      float w[8] = {w0.x, w0.y, w0.z, w0.w, w1.x, w1.y, w1.z, w1.w};
#pragma unroll
      for (int i = 0; i < 8; i++)
#pragma unroll
        for (int j = 0; j < 8; j++) acc[i][j] = fmaf(a[i], w[j], acc[i][j]);
    }
  }
#pragma unroll
  for (int i = 0; i < 8; i++) {
    const int m = row0 + ty * 8 + i;
    if (m < M) {
      float* crow = C + (long)m * ldc;
#pragma unroll
      for (int j = 0; j < 8; j++) {
        const int n = col0 + tx * 8 + j;
        if (n < N) crow[n] = acc[i][j] + (bias ? bias[n] : 0.f);
      }
    }
  }
}

__global__ __launch_bounds__(256) void transpose_x(
    const float* __restrict__ x, float* __restrict__ xt)
{
  const int i = blockIdx.x * 256 + threadIdx.x;
  if (i >= T_ * B_ * FEAT_) return;
  const int f = i % FEAT_;
  const int r = i / FEAT_;
  const int b = r % B_;
  const int t = r / B_;
  xt[i] = x[((long)b * T_ + t) * FEAT_ + f];
}

// one time step, both directions. grid = 256 WGs:
//   wg = dir*128 + bg*32 + chunk ; WG covers b in [bg*4, +4), jj in [chunk*16, +16)
// gxF/gxB are CH_-step chunk buffers; ls = step - chunk_start.
__global__ __launch_bounds__(256) void lstm_step(
    const float* __restrict__ gxF,     // [CH][B][4H] fwd x-gates (+bias)
    const float* __restrict__ gxB,     // [CH][B][4H] bwd x-gates, lt = CH-1-ls
    const float* __restrict__ hprev,   // [2][B][H]
    float* __restrict__ hnext,         // [2][B][H]
    float* __restrict__ cstate,        // [2][B][H]
    float* __restrict__ outb,          // [T][B][2H]
    const float* __restrict__ WhhF,    // [4H][H]
    const float* __restrict__ WhhB,    // [4H][H]
    const int* __restrict__ lengths, int step, int ls)
{
  __shared__ float hs[4][516];
  __shared__ float gs[4][4][16];
  const int wg = blockIdx.x;
  const int dir = wg >> 7, rem = wg & 127;
  const int bg = rem >> 5, chunk = rem & 31;
  const int tid = threadIdx.x;
#pragma unroll
  for (int j = 0; j < 8; j++) {
    const int flat = tid + j * 256;
    hs[flat >> 9][flat & 511] =
        hprev[(dir * B_ + bg * 4 + (flat >> 9)) * H_ + (flat & 511)];
  }
  __syncthreads();
  const int bloc = tid & 3, rest = tid >> 2;
  const int jloc = rest & 15, gate = rest >> 4;
  const int b = bg * 4 + bloc, jj = chunk * 16 + jloc;
  const int row = gate * H_ + jj;
  const int t = dir ? (T_ - 1 - step) : step;
  const float* Whh = dir ? WhhB : WhhF;
  const float* gsrc = dir ? (gxB + ((long)(CH_ - 1 - ls) * B_ + b) * H4_)
                          : (gxF + ((long)ls * B_ + b) * H4_);
  float acc = gsrc[row];
  const float* wr = Whh + (long)row * H_;
  const float* hv = hs[bloc];
#pragma unroll 8
  for (int k = 0; k < H_; k += 4) {
    float4 w4 = *(const float4*)(wr + k);
    float4 h4 = *(const float4*)(hv + k);
    acc = fmaf(w4.x, h4.x, acc);
    acc = fmaf(w4.y, h4.y, acc);
    acc = fmaf(w4.z, h4.z, acc);
    acc = fmaf(w4.w, h4.w, acc);
  }
  gs[gate][bloc][jloc] = acc;
  __syncthreads();
  if (tid < 64) {
    const int bl = tid & 3, jl = tid >> 2;
    const int bb = bg * 4 + bl, j2 = chunk * 16 + jl;
    const float gi = gs[0][bl][jl], gf = gs[1][bl][jl];
    const float gc = gs[2][bl][jl], go = gs[3][bl][jl];
    const float iv = 1.f / (1.f + expf(-gi));
    const float fv = 1.f / (1.f + expf(-gf));
    const float gv = tanhf(gc);
    const float ov = 1.f / (1.f + expf(-go));
    const int sidx = (dir * B_ + bb) * H_ + j2;
    const float c_old = cstate[sidx];
    const float h_old = hs[bl][j2];
    const float cn = fv * c_old + iv * gv;
    const float hn = ov * tanhf(cn);
    const bool mk = t < lengths[bb];
    cstate[sidx] = mk ? cn : c_old;
    hnext[sidx] = mk ? hn : h_old;
    outb[((long)t * B_ + bb) * H2_ + dir * H_ + j2] = mk ? hn : 0.f;
  }
}

// out[b][n] = [bias[n]] + [pre[b][n]] + S1[b]·W1[n] + [S2[b]·W2[n]]  ([tanh])
template <int ACT>
__global__ __launch_bounds__(256) void dotbn(
    const float* __restrict__ S1, const float* __restrict__ W1, int K1,
    const float* __restrict__ S2, const float* __restrict__ W2, int K2,
    const float* __restrict__ pre, int preStride,
    const float* __restrict__ bias,
    float* __restrict__ outp, int outStride, int N)
{
  const int idx = blockIdx.x * 256 + threadIdx.x;
  if (idx >= N * B_) return;
  const int b = idx & 15, n = idx >> 4;
  float acc = bias ? bias[n] : 0.f;
  if (pre) acc += pre[(long)b * preStride + n];
  {
    const float* s = S1 + (long)b * K1;
    const float* w = W1 + (long)n * K1;
#pragma unroll 4
    for (int k = 0; k < K1; k += 4) {
      float4 sv = *(const float4*)(s + k);
      float4 wv = *(const float4*)(w + k);
      acc = fmaf(sv.x, wv.x, acc); acc = fmaf(sv.y, wv.y, acc);
      acc = fmaf(sv.z, wv.z, acc); acc = fmaf(sv.w, wv.w, acc);
    }
  }
  if (S2) {
    const float* s = S2 + (long)b * K2;
    const float* w = W2 + (long)n * K2;
#pragma unroll 4
    for (int k = 0; k < K2; k += 4) {
      float4 sv = *(const float4*)(s + k);
      float4 wv = *(const float4*)(w + k);
      acc = fmaf(sv.x, wv.x, acc); acc = fmaf(sv.y, wv.y, acc);
      acc = fmaf(sv.z, wv.z, acc); acc = fmaf(sv.w, wv.w, acc);
    }
  }
  if (ACT == 1) acc = tanhf(acc);
  outp[(long)b * outStride + n] = acc;
}

__global__ __launch_bounds__(256) void dec_conv(
    const float* __restrict__ alpha, const float* __restrict__ cw,
    float* __restrict__ conv)
{
  const int idx = blockIdx.x * 256 + threadIdx.x;
  if (idx >= B_ * 10 * T_) return;
  const int t = idx % T_;
  const int f = (idx / T_) % 10;
  const int b = idx / (10 * T_);
  const float* a = alpha + b * T_;
  const float* w = cw + f * 100;
  float acc = 0.f;
  const int k0 = (50 - t) > 0 ? (50 - t) : 0;
  const int k1 = (T_ + 50 - t) < 100 ? (T_ + 50 - t) : 100;
  for (int k = k0; k < k1; k++) acc = fmaf(a[t + k - 50], w[k], acc);
  conv[idx] = acc;
}

// e[b][t] = sum_d tanh(se[b][d] + he[t,b][d] + sum_f conv[b][f][t]*W_fe[d][f]) * W_ee[d]
__global__ __launch_bounds__(256) void att_e(
    const float* __restrict__ se, const float* __restrict__ he,
    const float* __restrict__ conv, const float* __restrict__ W_fe,
    const float* __restrict__ W_ee, float* __restrict__ e)
{
  __shared__ float wfe[10240];
  __shared__ float ses[1024];
  __shared__ float wee[1024];
  __shared__ float red[4];
  const int wg = blockIdx.x;
  const int b = wg / 50, t0 = (wg % 50) * 16;
  const int tid = threadIdx.x;
  for (int i = tid; i < 10240; i += 256) wfe[i] = W_fe[i];
  for (int i = tid; i < 1024; i += 256) {
    ses[i] = se[b * H2_ + i];
    wee[i] = W_ee[i];
  }
  __syncthreads();
  for (int tt = 0; tt < 16; tt++) {
    const int t = t0 + tt;
    float cv[10];
#pragma unroll
    for (int f = 0; f < 10; f++) cv[f] = conv[(b * 10 + f) * T_ + t];
    const float* hrow = he + ((long)t * B_ + b) * H2_;
    float part = 0.f;
#pragma unroll
    for (int q = 0; q < 4; q++) {
      const int d = tid + q * 256;
      float loc = 0.f;
      const float* wf = &wfe[d * 10];
#pragma unroll
      for (int f = 0; f < 10; f++) loc = fmaf(cv[f], wf[f], loc);
      const float val = tanhf(ses[d] + hrow[d] + loc);
      part = fmaf(val, wee[d], part);
    }
#pragma unroll
    for (int off = 32; off; off >>= 1) part += __shfl_down(part, off);
    if ((tid & 63) == 0) red[tid >> 6] = part;
    __syncthreads();
    if (tid == 0) e[b * T_ + t] = red[0] + red[1] + red[2] + red[3];
    __syncthreads();
  }
}

__global__ __launch_bounds__(256) void att_softmax(
    const float* __restrict__ e, const int* __restrict__ lengths,
    float* __restrict__ alpha)
{
  __shared__ float red[4];
  __shared__ float bc, bc2;
  const int b = blockIdx.x, tid = threadIdx.x;
  const int len = lengths[b];
  float v[4];
  float mx = -1e30f;
#pragma unroll
  for (int q = 0; q < 4; q++) {
    const int t = tid + q * 256;
    v[q] = (t < T_) ? e[b * T_ + t] : -1e30f;
    mx = fmaxf(mx, v[q]);
  }
#pragma unroll
  for (int off = 32; off; off >>= 1) mx = fmaxf(mx, __shfl_down(mx, off));
  if ((tid & 63) == 0) red[tid >> 6] = mx;
  __syncthreads();
  if (tid == 0) bc = fmaxf(fmaxf(red[0], red[1]), fmaxf(red[2], red[3]));
  __syncthreads();
  const float m = bc;
  float ex[4];
  float s = 0.f;
#pragma unroll
  for (int q = 0; q < 4; q++) {
    const int t = tid + q * 256;
    ex[q] = (t < T_ && t < len) ? expf(v[q] - m) : 0.f;
    s += ex[q];
  }
#pragma unroll
  for (int off = 32; off; off >>= 1) s += __shfl_down(s, off);
  __syncthreads();
  if ((tid & 63) == 0) red[tid >> 6] = s;
  __syncthreads();
  if (tid == 0) bc2 = red[0] + red[1] + red[2] + red[3];
  __syncthreads();
  const float inv = 1.f / bc2;
#pragma unroll
  for (int q = 0; q < 4; q++) {
    const int t = tid + q * 256;
    if (t < T_) alpha[b * T_ + t] = ex[q] * inv;
  }
}

__global__ __launch_bounds__(256) void att_g(
    const float* __restrict__ alpha, const float* __restrict__ hb,
    float* __restrict__ g)
{
  const int idx = blockIdx.x * 256 + threadIdx.x;
  const int d = idx & (H2_ - 1), b = idx >> 10;
  const float* ab = alpha + b * T_;
  float acc = 0.f;
#pragma unroll 8
  for (int t = 0; t < T_; t++)
    acc = fmaf(ab[t], hb[((long)t * B_ + b) * H2_ + d], acc);
  g[idx] = acc;
}

__global__ __launch_bounds__(256) void dec_update(
    const float* __restrict__ rec, float* __restrict__ s, float* __restrict__ c)
{
  const int idx = blockIdx.x * 256 + threadIdx.x;
  if (idx >= B_ * H_) return;
  const int jj = idx & 511, b = idx >> 9;
  const float* r = rec + b * H4_;
  const float gi = r[jj], gf = r[jj + 512], gc = r[jj + 1024], go = r[jj + 1536];
  const float iv = tanhf(gi * 0.5f) * 0.5f + 0.5f;
  const float fv = tanhf(gf * 0.5f) * 0.5f + 0.5f;
  const float cg = tanhf(gc);
  const float ov = tanhf(go * 0.5f) * 0.5f + 0.5f;
  const float cn = fv * c[idx] + iv * cg;
  const float sn = ov * tanhf(cn);
  c[idx] = cn;
  s[idx] = sn;
}

extern "C" void kernel_launch(void* const* d_in, const int* in_sizes, int n_in,
                              void* d_out, int out_size, void* d_ws, size_t ws_size,
                              hipStream_t stream)
{
  const float* x       = (const float*)d_in[0];
  const int*   lengths = (const int*)  d_in[1];
  const float* target  = (const float*)d_in[2];
  const float* Wih0    = (const float*)d_in[3];
  const float* Whh0    = (const float*)d_in[4];
  const float* b0      = (const float*)d_in[5];
  const float* WihL    = (const float*)d_in[6];
  const float* WhhL    = (const float*)d_in[7];
  const float* bL      = (const float*)d_in[8];
  const float* W_se    = (const float*)d_in[9];
  const float* W_he    = (const float*)d_in[10];
  const float* b_he    = (const float*)d_in[11];
  const float* W_ee    = (const float*)d_in[12];
  const float* conv_w  = (const float*)d_in[13];
  const float* W_fe    = (const float*)d_in[14];
  const float* W_sy    = (const float*)d_in[15];
  const float* W_gy    = (const float*)d_in[16];
  const float* b_gy    = (const float*)d_in[17];
  const float* W_yy    = (const float*)d_in[18];
  const float* b_yy    = (const float*)d_in[19];
  const float* W_ys    = (const float*)d_in[20];
  const float* W_ss    = (const float*)d_in[21];
  const float* W_gs    = (const float*)d_in[22];
  const float* b_gs    = (const float*)d_in[23];
  float* out = (float*)d_out;

  // ---- workspace layout (119.1 MB total) ----
  float* bufA = (float*)d_ws;                      // [T][B][2H]  52.4MB
  float* bufB = bufA + (size_t)T_ * B_ * H2_;      // [T][B][2H]  52.4MB
  float* gxc  = bufB + (size_t)T_ * B_ * H2_;      // [2][CH][B][4H] 13.1MB
  float* gxcF = gxc;
  float* gxcB = gxc + (size_t)CH_ * B_ * H4_;
  float* he   = bufB;                              // decoder overlay (bufB free)
  float* ysp  = gxc;                               // decoder overlay (gxc free)
  float* st   = gxc + (size_t)2 * CH_ * B_ * H4_;
  float* h0   = st;
  float* h1   = h0 + 2 * B_ * H_;
  float* cs   = h1 + 2 * B_ * H_;
  float* sdec = cs + 2 * B_ * H_;
  float* cdec = sdec + B_ * H_;
  float* alpha= cdec + B_ * H_;
  float* conv = alpha + B_ * T_;
  float* ebuf = conv + B_ * 10 * T_;
  float* sebuf= ebuf + B_ * T_;
  float* gvec = sebuf + B_ * H2_;
  float* zvec = gvec + B_ * H2_;
  float* rec  = zvec + B_ * H_;

  // ---- encoder ----
  transpose_x<<<(T_ * B_ * FEAT_ + 255) / 256, 256, 0, stream>>>(x, bufA);

  float* inb  = bufA;
  float* outb = bufB;
  for (int l = 0; l < 4; l++) {
    const int Kin = (l == 0) ? FEAT_ : H2_;
    const float *WihF, *WihB, *WhhF, *WhhB, *bF, *bB;
    if (l == 0) {
      WihF = Wih0;                 WihB = Wih0 + (size_t)H4_ * FEAT_;
      WhhF = Whh0;                 WhhB = Whh0 + (size_t)H4_ * H_;
      bF = b0;                     bB = b0 + H4_;
    } else {
      const size_t o = (size_t)(l - 1) * 2;
      WihF = WihL + o * H4_ * H2_; WihB = WihF + (size_t)H4_ * H2_;
      WhhF = WhhL + o * H4_ * H_;  WhhB = WhhF + (size_t)H4_ * H_;
      bF = bL + o * H4_;           bB = bF + H4_;
    }
    (void)hipMemsetAsync(h0, 0, (size_t)3 * 2 * B_ * H_ * sizeof(float), stream);
    dim3 gg(H4_ / BN, (CH_ * B_ + BM - 1) / BM);  // (16, 7)
    for (int c = 0; c < T_ / CH_; c++) {
      const int s0 = c * CH_;
      gemm_bt<<<gg, 256, 0, stream>>>(inb + (size_t)s0 * B_ * Kin, WihF, bF,
                                      gxcF, CH_ * B_, H4_, Kin, H4_);
      gemm_bt<<<gg, 256, 0, stream>>>(inb + (size_t)(T_ - s0 - CH_) * B_ * Kin,
                                      WihB, bB, gxcB, CH_ * B_, H4_, Kin, H4_);
      for (int s = s0; s < s0 + CH_; s++) {
        float* hp = (s & 1) ? h1 : h0;
        float* hn = (s & 1) ? h0 : h1;
        lstm_step<<<256, 256, 0, stream>>>(gxcF, gxcB, hp, hn, cs, outb,
                                           WhhF, WhhB, lengths, s, s - s0);
      }
    }
    float* tmp = inb; inb = outb; outb = tmp;
  }
  float* hb = inb;  // final encoder output = bufA, [T][B][2H]

  // ---- decoder precompute ----
  {
    dim3 ghe(H2_ / BN, (T_ * B_) / BM);  // (8, 100)
    gemm_bt<<<ghe, 256, 0, stream>>>(hb, W_he, b_he, he, T_ * B_, H2_, H2_, H2_);
    dim3 gys(H4_ / BN, (B_ * NL_ + BM - 1) / BM);  // (16, 13)
    gemm_bt<<<gys, 256, 0, stream>>>(target, W_ys, b_gs, ysp, B_ * NL_, H4_, CC_, H4_);
  }
  (void)hipMemsetAsync(sdec, 0, (size_t)(2 * B_ * H_ + B_ * T_) * sizeof(float), stream);

  // ---- decoder steps ----
  for (int step = 0; step < NL_; step++) {
    dec_conv<<<(B_ * 10 * T_ + 255) / 256, 256, 0, stream>>>(alpha, conv_w, conv);
    dotbn<0><<<(B_ * H2_) / 256, 256, 0, stream>>>(
        sdec, W_se, H_, nullptr, nullptr, 0, nullptr, 0, nullptr, sebuf, H2_, H2_);
    att_e<<<800, 256, 0, stream>>>(sebuf, he, conv, W_fe, W_ee, ebuf);
    att_softmax<<<B_, 256, 0, stream>>>(ebuf, lengths, alpha);
    att_g<<<(B_ * H2_) / 256, 256, 0, stream>>>(alpha, hb, gvec);
    dotbn<1><<<(B_ * H_) / 256, 256, 0, stream>>>(
        gvec, W_gy, H2_, sdec, W_sy, H_, nullptr, 0, b_gy, zvec, H_, H_);
    dotbn<0><<<(B_ * CC_ + 255) / 256, 256, 0, stream>>>(
        zvec, W_yy, H_, nullptr, nullptr, 0, nullptr, 0, b_yy,
        out + (size_t)step * CC_, NL_ * CC_, CC_);
    dotbn<0><<<(B_ * H4_) / 256, 256, 0, stream>>>(
        sdec, W_ss, H_, gvec, W_gs, H2_, ysp + (size_t)step * H4_, NL_ * H4_,
        nullptr, rec, H4_, H4_);
    dec_update<<<(B_ * H_) / 256, 256, 0, stream>>>(rec, sdec, cdec);
  }
}